// Round 3
// baseline (44.135 us; speedup 1.0000x reference)
//
#include <hip/hip_runtime.h>
#include <float.h>

#define BB 4
#define NN 2048
#define SS 256
#define FF 7680   // C_FEAT * NA = 128*60
#define PP 24
#define TF 64     // f-rows per k3 block

#define KVPAD(s) ((s) + ((s) >> 5))

// ws layout (floats): [0,128) denom[b][p], [128, 128+BB*SS*PP) A_T[b][s][p],
//                     then per-chunk partials

// branchless insert of (v, vi) into ascending triple, strict < (incumbent wins ties)
#define INSERT3(v, vi)                                                       \
    {                                                                        \
        bool c0 = (v) < t0, c1 = (v) < t1, c2 = (v) < t2;                    \
        float n2 = c1 ? t1 : (c2 ? (v) : t2);                                \
        int m2 = c1 ? j1 : (c2 ? (vi) : j2);                                 \
        float n1 = c0 ? t0 : (c1 ? (v) : t1);                                \
        int m1 = c0 ? j0 : (c1 ? (vi) : j1);                                 \
        t0 = c0 ? (v) : t0;                                                  \
        j0 = c0 ? (vi) : j0;                                                 \
        t1 = n1; j1 = m1; t2 = n2; j2 = m2;                                  \
    }

// merge partner's triple; lower-s-range thread's triple is the base (wins ties)
#define MERGE_ROUND(m)                                                       \
    {                                                                        \
        float q0 = __shfl_xor(t0, (m)), q1 = __shfl_xor(t1, (m)),            \
              q2 = __shfl_xor(t2, (m));                                      \
        int r0 = __shfl_xor(j0, (m)), r1 = __shfl_xor(j1, (m)),              \
            r2 = __shfl_xor(j2, (m));                                        \
        bool lw = ((h & (m)) == 0);                                          \
        float is0 = lw ? q0 : t0, is1 = lw ? q1 : t1, is2 = lw ? q2 : t2;    \
        int ij0 = lw ? r0 : j0, ij1 = lw ? r1 : j1, ij2 = lw ? r2 : j2;      \
        float bs0 = lw ? t0 : q0, bs1 = lw ? t1 : q1, bs2 = lw ? t2 : q2;    \
        int bj0 = lw ? j0 : r0, bj1 = lw ? j1 : r1, bj2 = lw ? j2 : r2;      \
        t0 = bs0; t1 = bs1; t2 = bs2; j0 = bj0; j1 = bj1; j2 = bj2;          \
        INSERT3(is0, ij0);                                                   \
        INSERT3(is1, ij1);                                                   \
        INSERT3(is2, ij2);                                                   \
    }

// ---------------- kernel 2: 3-NN + scatter into per-block partial A + denom ----------------
// TPN threads per n; block covers NPB=256/TPN n's; each thread scans SS/TPN s's.
template <int TPN, bool ATOMIC_OUT>
__global__ __launch_bounds__(256) void k2_scatter(const float* __restrict__ xyz1,
                                                  const float* __restrict__ xyz2,
                                                  const float* __restrict__ ps,
                                                  float* __restrict__ dst,
                                                  float* __restrict__ denom) {
    constexpr int NPB = 256 / TPN;
    constexpr int CHUNKS = NN / NPB;
    constexpr int SPT = SS / TPN;
    constexpr int PPT = PP / TPN;
    int b = blockIdx.x / CHUNKS;
    int chunk = blockIdx.x % CHUNKS;
    int tid = threadIdx.x;

    __shared__ float4 kv[SS + (SS >> 5)];
    __shared__ float aloc[SS][PP];
    __shared__ float dsum[PP];

    {   // stage sparse coords + |p|^2, bank-swizzled
        int s = tid;
        float x = xyz2[b * 3 * SS + s];
        float y = xyz2[b * 3 * SS + SS + s];
        float z = xyz2[b * 3 * SS + 2 * SS + s];
        kv[KVPAD(s)] = make_float4(x, y, z, x * x + y * y + z * z);
    }
    for (int i = tid; i < SS * PP; i += 256) ((float*)aloc)[i] = 0.f;
    if (tid < PP) dsum[tid] = 0.f;
    __syncthreads();

    int h = tid % TPN;
    int n = chunk * NPB + tid / TPN;
    const float* x1p = xyz1 + ((size_t)b * NN + n) * 3;
    float x = x1p[0], y = x1p[1], z = x1p[2];
    float x1sq = x * x + y * y + z * z;

    float t0 = FLT_MAX, t1 = FLT_MAX, t2 = FLT_MAX;
    int j0 = 0, j1 = 0, j2 = 0;
    int sbeg = h * SPT;
#pragma unroll 4
    for (int s = sbeg; s < sbeg + SPT; ++s) {
        float4 c = kv[KVPAD(s)];
        float dt = x * c.x;
        dt = fmaf(y, c.y, dt);
        dt = fmaf(z, c.z, dt);
        float d = fmaf(-2.f, dt, x1sq + c.w);
        INSERT3(d, s);
    }
#pragma unroll
    for (int m = 1; m < TPN; m <<= 1) { MERGE_ROUND(m); }

    float w0 = 1.f / (t0 + 1e-8f);
    float w1 = 1.f / (t1 + 1e-8f);
    float w2 = 1.f / (t2 + 1e-8f);
    float wsum = w0 + w1 + w2;
    w0 /= wsum; w1 /= wsum; w2 /= wsum;

    // scatter + denom partials: this thread handles PPT of the 24 parts for its n
    const float* prow = ps + ((size_t)b * NN + n) * PP + h * PPT;
#pragma unroll
    for (int j = 0; j < PPT; ++j) {
        float v = prow[j];
        atomicAdd(&dsum[h * PPT + j], fabsf(v));
        atomicAdd(&aloc[j0][h * PPT + j], v * w0);
        atomicAdd(&aloc[j1][h * PPT + j], v * w1);
        atomicAdd(&aloc[j2][h * PPT + j], v * w2);
    }
    __syncthreads();

    if (ATOMIC_OUT) {
        int s = tid;
        float* d2 = dst + ((size_t)b * SS + s) * PP;
#pragma unroll
        for (int p = 0; p < PP; ++p) unsafeAtomicAdd(&d2[p], aloc[s][p]);
    } else {
        float* d2 = dst + (size_t)blockIdx.x * (SS * PP);
        for (int i = tid; i < SS * PP; i += 256) d2[i] = ((float*)aloc)[i];
    }
    if (tid < PP) unsafeAtomicAdd(&denom[b * PP + tid], dsum[tid]);
}

// ---------------- kernel 2b: A_T[b][s][p] = sum_chunk partial[b][chunk][s][p] ----------------
template <int CHUNKS>
__global__ __launch_bounds__(256) void k2b_reduce(const float* __restrict__ partial,
                                                  float* __restrict__ aT) {
    int i = blockIdx.x * 256 + threadIdx.x;   // over BB*SS*PP
    int b = i / (SS * PP);
    int sp = i - b * (SS * PP);
    const float* src = partial + ((size_t)b * CHUNKS) * (SS * PP) + sp;
    float acc = 0.f;
#pragma unroll 4
    for (int c = 0; c < CHUNKS; ++c) acc += src[(size_t)c * (SS * PP)];
    aT[i] = acc;
}

// ---------------- kernel 3: out[b,p,f] = (1/den[b,p]) * sum_s A_T[b,s,p]*pts2[b,f,s] ----------------
// Block: 64-f tile. Stage contiguous 64 KB pts2 tile into XOR-swizzled LDS (float4
// granularity), then lane=f / wave=s-quarter compute with conflict-free ds_read_b128.
__global__ __launch_bounds__(256) void k3_contract(const float* __restrict__ pts2,
                                                   const float* __restrict__ aT,
                                                   const float* __restrict__ denom,
                                                   float* __restrict__ out) {
    int bb = blockIdx.x;
    int b = bb / (FF / TF);
    int fbase = (bb % (FF / TF)) * TF;
    int tid = threadIdx.x;

    __shared__ float4 xs4[TF * 64];   // exactly 64 KiB

    // coalesced staging: tile is a contiguous 64 KB block of global memory
    const float4* src = (const float4*)(pts2 + ((size_t)b * FF + fbase) * SS);
#pragma unroll 8
    for (int t = tid; t < TF * 64; t += 256) {
        int f = t >> 6;
        int c4 = t & 63;
        xs4[f * 64 + (c4 ^ (f & 7))] = src[t];
    }
    __syncthreads();

    int q = __builtin_amdgcn_readfirstlane(tid >> 6);  // wave-uniform s-quarter
    int fl = tid & 63;                                  // lane = f within tile

    const float* arow = aT + ((size_t)b * SS + q * 64) * PP;  // uniform -> s_load

    float acc[PP];
#pragma unroll
    for (int p = 0; p < PP; ++p) acc[p] = 0.f;

    int rbase = fl * 64;
    int cb = q * 16;
#pragma unroll 2
    for (int ii = 0; ii < 16; ++ii) {
        float4 xv = xs4[rbase + ((cb + ii) ^ (fl & 7))];
        const float* ar = arow + (ii * 4) * PP;
#pragma unroll
        for (int p = 0; p < PP; ++p) acc[p] = fmaf(ar[p], xv.x, acc[p]);
#pragma unroll
        for (int p = 0; p < PP; ++p) acc[p] = fmaf(ar[PP + p], xv.y, acc[p]);
#pragma unroll
        for (int p = 0; p < PP; ++p) acc[p] = fmaf(ar[2 * PP + p], xv.z, acc[p]);
#pragma unroll
        for (int p = 0; p < PP; ++p) acc[p] = fmaf(ar[3 * PP + p], xv.w, acc[p]);
    }

    __syncthreads();                  // all xs4 reads done; alias for reduction
    float* part = (float*)xs4;        // [256][25]
#pragma unroll
    for (int p = 0; p < PP; ++p) part[tid * 25 + p] = acc[p];
    __syncthreads();

    int fl2 = tid & 63;
    int pg = tid >> 6;
#pragma unroll
    for (int j = 0; j < 6; ++j) {
        int p = pg * 6 + j;
        float v = part[(0 * 64 + fl2) * 25 + p] + part[(1 * 64 + fl2) * 25 + p] +
                  part[(2 * 64 + fl2) * 25 + p] + part[(3 * 64 + fl2) * 25 + p];
        float den = denom[b * PP + p];
        v *= 1.0f / fmaxf(den, 1e-12f);
        out[((size_t)b * PP + p) * FF + fbase + fl2] = v;
    }
}

extern "C" void kernel_launch(void* const* d_in, const int* in_sizes, int n_in,
                              void* d_out, int out_size, void* d_ws, size_t ws_size,
                              hipStream_t stream) {
    const float* xyz1 = (const float*)d_in[0];
    const float* xyz2 = (const float*)d_in[1];
    const float* pts2 = (const float*)d_in[2];
    const float* ps   = (const float*)d_in[3];
    float* out = (float*)d_out;
    float* denom = (float*)d_ws;
    float* aT = (float*)d_ws + 128;
    float* partial = (float*)d_ws + 128 + BB * SS * PP;

    const size_t baseFloats = 128 + (size_t)BB * SS * PP;
    auto need = [&](int chunksTotal) {
        return (baseFloats + (size_t)chunksTotal * SS * PP) * sizeof(float);
    };

    if (ws_size >= need(BB * 64)) {
        hipMemsetAsync(d_ws, 0, 128 * sizeof(float), stream);
        k2_scatter<8, false><<<BB * 64, 256, 0, stream>>>(xyz1, xyz2, ps, partial, denom);
        k2b_reduce<64><<<(BB * SS * PP) / 256, 256, 0, stream>>>(partial, aT);
    } else if (ws_size >= need(BB * 32)) {
        hipMemsetAsync(d_ws, 0, 128 * sizeof(float), stream);
        k2_scatter<4, false><<<BB * 32, 256, 0, stream>>>(xyz1, xyz2, ps, partial, denom);
        k2b_reduce<32><<<(BB * SS * PP) / 256, 256, 0, stream>>>(partial, aT);
    } else {
        hipMemsetAsync(d_ws, 0, baseFloats * sizeof(float), stream);
        k2_scatter<2, true><<<BB * 16, 256, 0, stream>>>(xyz1, xyz2, ps, aT, denom);
    }

    k3_contract<<<BB * (FF / TF), 256, 0, stream>>>(pts2, aT, denom, out);
}